// Round 23
// baseline (239.004 us; speedup 1.0000x reference)
//
#include <hip/hip_runtime.h>
#include <hip/hip_bf16.h>

// d_out is FLOAT32. h_pen = first N*256 f32, h = next N*128 f32.

using bf16 = __hip_bfloat16;

typedef __attribute__((ext_vector_type(8))) short bf16x8;
typedef __attribute__((ext_vector_type(4))) short short4v;
typedef __attribute__((ext_vector_type(4))) float f32x4;
typedef __attribute__((ext_vector_type(2))) unsigned int uint2v;

__device__ __forceinline__ float u2f(unsigned u) { union { float f; unsigned u; } c; c.u = u; return c.f; }
__device__ __forceinline__ unsigned f2u(float x) { union { float f; unsigned u; } c; c.f = x; return c.u; }
__device__ __forceinline__ short bfbits(float x) {
  unsigned xu = f2u(x);
  return (short)((xu + 0x7FFF + ((xu >> 16) & 1)) >> 16);
}

// ============================ CSR build (dst-sorted) ============================
__global__ void hist_kernel(const int* __restrict__ ei, int E, int N, int* __restrict__ cnt) {
  int e = blockIdx.x * 256 + threadIdx.x;
  if (e >= E + N) return;
  int dst = (e < E) ? ei[E + e] : (e - E);
  atomicAdd(&cnt[dst], 1);
}

__global__ __launch_bounds__(1024) void scan_kernel(const int* __restrict__ cnt,
                                                    int* __restrict__ row_start, int N) {
  __shared__ int part[1024];
  int t = threadIdx.x;
  int chunk = (N + 1023) / 1024;
  int lo = t * chunk; if (lo > N) lo = N;
  int hi = lo + chunk; if (hi > N) hi = N;
  int s = 0;
  for (int i = lo; i < hi; ++i) s += cnt[i];
  part[t] = s;
  __syncthreads();
  for (int off = 1; off < 1024; off <<= 1) {
    int add = (t >= off) ? part[t - off] : 0;
    __syncthreads();
    part[t] += add;
    __syncthreads();
  }
  int run = part[t] - s;
  for (int i = lo; i < hi; ++i) { row_start[i] = run; run += cnt[i]; }
  if (t == 1023) row_start[N] = part[1023];
}

__global__ void scatter_kernel(const int* __restrict__ ei, int E, int N,
                               const int* __restrict__ row_start, int* __restrict__ cursor,
                               int* __restrict__ csr_src) {
  int e = blockIdx.x * 256 + threadIdx.x;
  if (e >= E + N) return;
  int src, dst;
  if (e < E) { src = ei[e]; dst = ei[E + e]; }
  else       { src = e - E; dst = e - E; }
  int pos = atomicAdd(&cursor[dst], 1);
  csr_src[row_start[dst] + pos] = src;
}

// ============================ W (f32) -> split + MFMA fragment order + zero as_/ad_ ============================
__global__ void prefrag_kernel(const float* __restrict__ W0, const float* __restrict__ W1,
                               const float* __restrict__ W2,
                               unsigned short* __restrict__ F0h, unsigned short* __restrict__ F0l,
                               unsigned short* __restrict__ F1h, unsigned short* __restrict__ F1l,
                               unsigned short* __restrict__ F2h, unsigned short* __restrict__ F2l,
                               float* __restrict__ z0, float* __restrict__ z1,
                               int c0, int c1, int c2, int nz) {
  int id = blockIdx.x * 256 + threadIdx.x;
  const float* W; unsigned short *Fh, *Fl; int K, ktmax, rid;
  if (id < c0)                { W = W0; Fh = F0h; Fl = F0l; K = 512; ktmax = 16; rid = id; }
  else if (id < c0 + c1)      { W = W1; Fh = F1h; Fl = F1l; K = 256; ktmax = 8;  rid = id - c0; }
  else if (id < c0 + c1 + c2) { W = W2; Fh = F2h; Fl = F2l; K = 256; ktmax = 8;  rid = id - c0 - c1; }
  else {
    int zi = id - c0 - c1 - c2;          // zero tail: as_[0..nz), ad_[0..nz)
    if (zi < nz) z0[zi] = 0.f;
    else if (zi < 2 * nz) z1[zi - nz] = 0.f;
    return;
  }
  int lane = rid & 63;
  int blk  = rid >> 6;              // jb*ktmax + kt32
  int jb   = blk / ktmax;
  int kt32 = blk % ktmax;
  int lr = lane & 15, g = lane >> 4;
  const float* s = W + (size_t)(jb * 16 + lr) * K + kt32 * 32;
  short4v h0, h1, l0, l1;
#pragma unroll
  for (int e = 0; e < 4; ++e) {
    float a = s[g * 4 + e];
    short hb = bfbits(a);
    h0[e] = hb; l0[e] = bfbits(a - u2f(((unsigned)(unsigned short)hb) << 16));
    float b = s[16 + g * 4 + e];
    short hb2 = bfbits(b);
    h1[e] = hb2; l1[e] = bfbits(b - u2f(((unsigned)(unsigned short)hb2) << 16));
  }
  size_t o = ((size_t)blk * 64 + lane) * 8;
  *(short4v*)(Fh + o)     = h0;
  *(short4v*)(Fh + o + 4) = h1;
  *(short4v*)(Fl + o)     = l0;
  *(short4v*)(Fl + o + 4) = l1;
}

// ============================ MFMA GEMM 64x64: A via LDS, B direct, coalesced C16 ============================
// ROW0: global row offset (for split-M dispatches). as_/ad_/C16 indexed by absolute row.
#define LDP 40  // LDS pitch in shorts

__device__ __forceinline__ bf16x8 make_frag(const short* S, int row, int g) {
  short4v klo = *(const short4v*)&S[row * LDP + g * 4];
  short4v khi = *(const short4v*)&S[row * LDP + 16 + g * 4];
  bf16x8 r;
#pragma unroll
  for (int i = 0; i < 4; ++i) { r[i] = klo[i]; r[i + 4] = khi[i]; }
  return r;
}

template <bool FUSE8, bool FUSE1>
__global__ __launch_bounds__(256) void gemm_mfma(const float* __restrict__ Af,
                                                 const unsigned short* __restrict__ Fh,
                                                 const unsigned short* __restrict__ Fl,
                                                 const float* __restrict__ Asrc,
                                                 const float* __restrict__ Adst,
                                                 float* __restrict__ as_,
                                                 float* __restrict__ ad_,
                                                 unsigned short* __restrict__ C16,
                                                 int row0, int M, int Nn, int K, int NB) {
  // XCD-aware: same-bm blocks differ by 8 in id -> same XCD -> A panel L2 reuse.
  int id = blockIdx.x;
  int r8 = id & 7;
  int q  = id >> 3;
  int bn = q % NB;
  int bm = r8 + 8 * (q / NB);
  if (row0 + bm * 64 >= M) return;

  __shared__ short Ah[64 * LDP];
  __shared__ short Al[64 * LDP];
  __shared__ short CT[4][16][64];
  int t = threadIdx.x;
  int w = t >> 6, l = t & 63;
  int g = l >> 4, lr = l & 15;
  int ktmax = K >> 5;

  f32x4 acc[4];
#pragma unroll
  for (int j = 0; j < 4; ++j) acc[j] = (f32x4)(0.f);

  int srow = t >> 2;
  int sseg = (t & 3) * 8;
  int gm = row0 + bm * 64 + srow;
  const float* Abase = Af + (size_t)gm * K + sseg;
  const unsigned short* FhL = Fh + (size_t)l * 8;
  const unsigned short* FlL = Fl + (size_t)l * 8;

  f32x4 va0 = (f32x4)(0.f), va1 = (f32x4)(0.f);
  if (gm < M) { va0 = *(const f32x4*)(Abase); va1 = *(const f32x4*)(Abase + 4); }

  for (int kt32 = 0; kt32 < ktmax; ++kt32) {
    short4v h0, l0, h1, l1;
#pragma unroll
    for (int i = 0; i < 4; ++i) {
      short hb0 = bfbits(va0[i]);
      l0[i] = bfbits(va0[i] - u2f(((unsigned)(unsigned short)hb0) << 16));
      h0[i] = hb0;
      short hb1 = bfbits(va1[i]);
      l1[i] = bfbits(va1[i] - u2f(((unsigned)(unsigned short)hb1) << 16));
      h1[i] = hb1;
    }
    __syncthreads();
    *(short4v*)&Ah[srow * LDP + sseg]     = h0;
    *(short4v*)&Ah[srow * LDP + sseg + 4] = h1;
    *(short4v*)&Al[srow * LDP + sseg]     = l0;
    *(short4v*)&Al[srow * LDP + sseg + 4] = l1;
    __syncthreads();

    if (kt32 + 1 < ktmax) {
      int k2 = (kt32 + 1) << 5;
      if (gm < M) { va0 = *(const f32x4*)(Abase + k2); va1 = *(const f32x4*)(Abase + k2 + 4); }
    }

    int arow = w * 16 + lr;
    bf16x8 ah = make_frag(Ah, arow, g);
    bf16x8 al = make_frag(Al, arow, g);
#pragma unroll
    for (int j = 0; j < 4; ++j) {
      size_t fo = ((size_t)((bn * 4 + j) * ktmax + kt32) * 64) * 8;
      bf16x8 bh = *(const bf16x8*)(FhL + fo);
      bf16x8 bl = *(const bf16x8*)(FlL + fo);
      acc[j] = __builtin_amdgcn_mfma_f32_16x16x32_bf16(ah, bh, acc[j], 0, 0, 0);
      acc[j] = __builtin_amdgcn_mfma_f32_16x16x32_bf16(al, bh, acc[j], 0, 0, 0);
      acc[j] = __builtin_amdgcn_mfma_f32_16x16x32_bf16(ah, bl, acc[j], 0, 0, 0);
    }
  }

  // ---- coalesced C16 write via per-wave LDS transpose (m89 layout) ----
#pragma unroll
  for (int j = 0; j < 4; ++j)
#pragma unroll
    for (int r = 0; r < 4; ++r)
      CT[w][g * 4 + r][j * 16 + lr] = bfbits(acc[j][r]);
  {
    int rrow = l >> 2, rseg = l & 3;
    int grow = row0 + bm * 64 + w * 16 + rrow;
    if (grow < M) {
      const short* src = &CT[w][rrow][rseg * 16];
      uint4 v0 = *(const uint4*)(src);
      uint4 v1 = *(const uint4*)(src + 8);
      unsigned short* dst = C16 + (size_t)grow * Nn + bn * 64 + rseg * 16;
      *(uint4*)dst = v0;
      *(uint4*)(dst + 8) = v1;
    }
  }

  if constexpr (FUSE8) {
    float cs[4], cd[4];
#pragma unroll
    for (int j = 0; j < 4; ++j) {
      cs[j] = Asrc[bn * 64 + j * 16 + lr];
      cd[j] = Adst[bn * 64 + j * 16 + lr];
    }
#pragma unroll
    for (int r = 0; r < 4; ++r) {
      float sA0 = acc[0][r] * cs[0] + acc[1][r] * cs[1];
      float sA1 = acc[2][r] * cs[2] + acc[3][r] * cs[3];
      float sD0 = acc[0][r] * cd[0] + acc[1][r] * cd[1];
      float sD1 = acc[2][r] * cd[2] + acc[3][r] * cd[3];
#pragma unroll
      for (int mask = 1; mask < 16; mask <<= 1) {
        sA0 += __shfl_xor(sA0, mask);
        sA1 += __shfl_xor(sA1, mask);
        sD0 += __shfl_xor(sD0, mask);
        sD1 += __shfl_xor(sD1, mask);
      }
      if (lr == 0) {
        int row = row0 + bm * 64 + w * 16 + g * 4 + r;
        if (row < M) {
          as_[row * 8 + bn * 2]     = sA0;
          as_[row * 8 + bn * 2 + 1] = sA1;
          ad_[row * 8 + bn * 2]     = sD0;
          ad_[row * 8 + bn * 2 + 1] = sD1;
        }
      }
    }
  }

  if constexpr (FUSE1) {
    float cs[4], cd[4];
#pragma unroll
    for (int j = 0; j < 4; ++j) {
      cs[j] = Asrc[bn * 64 + j * 16 + lr];
      cd[j] = Adst[bn * 64 + j * 16 + lr];
    }
#pragma unroll
    for (int r = 0; r < 4; ++r) {
      float sA = acc[0][r] * cs[0] + acc[1][r] * cs[1] + acc[2][r] * cs[2] + acc[3][r] * cs[3];
      float sD = acc[0][r] * cd[0] + acc[1][r] * cd[1] + acc[2][r] * cd[2] + acc[3][r] * cd[3];
#pragma unroll
      for (int mask = 1; mask < 16; mask <<= 1) {
        sA += __shfl_xor(sA, mask);
        sD += __shfl_xor(sD, mask);
      }
      if (lr == 0) {
        int row = row0 + bm * 64 + w * 16 + g * 4 + r;
        if (row < M) {
          atomicAdd(&as_[row], sA);
          atomicAdd(&ad_[row], sD);
        }
      }
    }
  }
}

// ============================ softmax + aggregate (bf16 gather, 4-deep, 4 nodes/block) ============================
template <int H, int C, bool RELU>
__global__ __launch_bounds__(256) void agg_kernel(const unsigned short* __restrict__ Hb16,
                                                  const float* __restrict__ as_,
                                                  const float* __restrict__ ad_,
                                                  const int* __restrict__ row_start,
                                                  const int* __restrict__ csr_src,
                                                  const float* __restrict__ bias,
                                                  float* __restrict__ out, int N) {
  int n = blockIdx.x * 4 + (threadIdx.x >> 6);
  if (n >= N) return;
  int l = threadIdx.x & 63;
  int s = row_start[n], e = row_start[n + 1];

  constexpr int LPH = 64 / H;
  constexpr int CPL = C / LPH;
  constexpr int HC = H * C;
  int h2 = l / LPH;
  int cb = (l % LPH) * CPL;
  float ad2 = ad_[n * H + h2];

  float acc[CPL];
#pragma unroll
  for (int c = 0; c < CPL; ++c) acc[c] = 0.f;
  float denom = 0.f;

  auto lrelu = [](float x) { return x > 0.f ? x : 0.2f * x; };

  int j = s;
  for (; j + 3 < e; j += 4) {
    int s0 = csr_src[j], s1 = csr_src[j + 1], s2 = csr_src[j + 2], s3 = csr_src[j + 3];
    float x0 = as_[s0 * H + h2], x1 = as_[s1 * H + h2];
    float x2 = as_[s2 * H + h2], x3 = as_[s3 * H + h2];
    const unsigned short* hp0 = Hb16 + (size_t)s0 * HC + h2 * C + cb;
    const unsigned short* hp1 = Hb16 + (size_t)s1 * HC + h2 * C + cb;
    const unsigned short* hp2 = Hb16 + (size_t)s2 * HC + h2 * C + cb;
    const unsigned short* hp3 = Hb16 + (size_t)s3 * HC + h2 * C + cb;
    float p0 = __expf(lrelu(x0 + ad2)), p1 = __expf(lrelu(x1 + ad2));
    float p2 = __expf(lrelu(x2 + ad2)), p3 = __expf(lrelu(x3 + ad2));
    denom += (p0 + p1) + (p2 + p3);
    if constexpr (CPL == 4) {
      uint2v u0 = *(const uint2v*)hp0;
      uint2v u1 = *(const uint2v*)hp1;
      uint2v u2 = *(const uint2v*)hp2;
      uint2v u3 = *(const uint2v*)hp3;
#pragma unroll
      for (int c = 0; c < 2; ++c) {
        acc[2 * c]     += p0 * u2f(u0[c] << 16)         + p1 * u2f(u1[c] << 16)
                        + p2 * u2f(u2[c] << 16)         + p3 * u2f(u3[c] << 16);
        acc[2 * c + 1] += p0 * u2f(u0[c] & 0xFFFF0000u) + p1 * u2f(u1[c] & 0xFFFF0000u)
                        + p2 * u2f(u2[c] & 0xFFFF0000u) + p3 * u2f(u3[c] & 0xFFFF0000u);
      }
    } else {
      unsigned u0 = *(const unsigned*)hp0;
      unsigned u1 = *(const unsigned*)hp1;
      unsigned u2 = *(const unsigned*)hp2;
      unsigned u3 = *(const unsigned*)hp3;
      acc[0] += p0 * u2f(u0 << 16)         + p1 * u2f(u1 << 16)
              + p2 * u2f(u2 << 16)         + p3 * u2f(u3 << 16);
      acc[1] += p0 * u2f(u0 & 0xFFFF0000u) + p1 * u2f(u1 & 0xFFFF0000u)
              + p2 * u2f(u2 & 0xFFFF0000u) + p3 * u2f(u3 & 0xFFFF0000u);
    }
  }
  for (; j < e; ++j) {
    int s0 = csr_src[j];
    float p0 = __expf(lrelu(as_[s0 * H + h2] + ad2));
    denom += p0;
    const unsigned short* hp0 = Hb16 + (size_t)s0 * HC + h2 * C + cb;
    if constexpr (CPL == 4) {
      uint2v u0 = *(const uint2v*)hp0;
#pragma unroll
      for (int c = 0; c < 2; ++c) {
        acc[2 * c]     += p0 * u2f(u0[c] << 16);
        acc[2 * c + 1] += p0 * u2f(u0[c] & 0xFFFF0000u);
      }
    } else {
      unsigned u0 = *(const unsigned*)hp0;
      acc[0] += p0 * u2f(u0 << 16);
      acc[1] += p0 * u2f(u0 & 0xFFFF0000u);
    }
  }

  float inv = 1.f / (denom + 1e-16f);
#pragma unroll
  for (int c = 0; c < CPL; ++c) {
    float v = acc[c] * inv + bias[h2 * C + cb + c];
    if (RELU) v = fmaxf(v, 0.f);
    out[(size_t)n * HC + h2 * C + cb + c] = v;
  }
}

// ============================ launch ============================
extern "C" void kernel_launch(void* const* d_in, const int* in_sizes, int n_in,
                              void* d_out, int out_size, void* d_ws, size_t ws_size,
                              hipStream_t stream) {
  const float* x    = (const float*)d_in[0];
  const int*   ei   = (const int*)d_in[1];
  const float* W0   = (const float*)d_in[2];
  const float* asr0 = (const float*)d_in[3];
  const float* adt0 = (const float*)d_in[4];
  const float* b0   = (const float*)d_in[5];
  const float* W1   = (const float*)d_in[6];
  const float* asr1 = (const float*)d_in[7];
  const float* adt1 = (const float*)d_in[8];
  const float* b1   = (const float*)d_in[9];
  const float* W2   = (const float*)d_in[10];
  const float* asr2 = (const float*)d_in[11];
  const float* adt2 = (const float*)d_in[12];
  const float* b2   = (const float*)d_in[13];

  const int FIN = 512, HID = 256, OUTC = 128;
  int N = in_sizes[0] / FIN;          // 20000
  int E = in_sizes[1] / 2;            // 320000
  int Etot = E + N;

  char* ws = (char*)d_ws;
  size_t off = 0;
  auto alloc = [&](size_t bytes) -> void* {
    void* p = ws + off;
    off = (off + bytes + 255) & ~(size_t)255;
    return p;
  };
  int* cnt       = (int*)alloc((size_t)N * 4);
  int* cursor    = (int*)alloc((size_t)N * 4);
  int* row_start = (int*)alloc((size_t)(N + 1) * 4);
  int* csr_src   = (int*)alloc((size_t)Etot * 4);
  float* as_     = (float*)alloc((size_t)N * 8 * 4);
  float* ad_     = (float*)alloc((size_t)N * 8 * 4);
  unsigned short* Hb16 = (unsigned short*)alloc((size_t)N * HID * 2);
  float* act     = (float*)alloc((size_t)N * HID * 4);
  unsigned short* F0h = (unsigned short*)alloc((size_t)HID * FIN * 2);
  unsigned short* F0l = (unsigned short*)alloc((size_t)HID * FIN * 2);
  unsigned short* F1h = (unsigned short*)alloc((size_t)HID * HID * 2);
  unsigned short* F1l = (unsigned short*)alloc((size_t)HID * HID * 2);
  unsigned short* F2h = (unsigned short*)alloc((size_t)OUTC * HID * 2);
  unsigned short* F2l = (unsigned short*)alloc((size_t)OUTC * HID * 2);

  float* hpen = (float*)d_out;
  float* out2 = (float*)d_out + (size_t)N * HID;

  // ---- split+fragment weights AND zero as_/ad_ (one launch) ----
  int c0 = (HID / 16) * (FIN / 32) * 64;
  int c1 = (HID / 16) * (HID / 32) * 64;
  int c2 = (OUTC / 16) * (HID / 32) * 64;
  int total = c0 + c1 + c2 + 2 * N;
  prefrag_kernel<<<(total + 255) / 256, 256, 0, stream>>>(
      W0, W1, W2, F0h, F0l, F1h, F1l, F2h, F2l, as_, ad_, c0, c1, c2, N);

  // ---- CSR build ----
  (void)hipMemsetAsync(cnt, 0, (size_t)((char*)cursor - (char*)cnt) + (size_t)N * 4, stream);
  int eb = (Etot + 255) / 256;
  hist_kernel<<<eb, 256, 0, stream>>>(ei, E, N, cnt);
  scan_kernel<<<1, 1024, 0, stream>>>(cnt, row_start, N);
  scatter_kernel<<<eb, 256, 0, stream>>>(ei, E, N, row_start, cursor, csr_src);

  int mb = (N + 63) / 64;          // 313
  int mb8 = (mb + 7) / 8;          // 40
  int grid4 = 8 * 4 * mb8;         // NB=4
  int grid2 = 8 * 2 * mb8;         // NB=2
  int gagg = (N + 3) / 4;

  // ---- layer 0: full-M dispatch ----
  gemm_mfma<true, false><<<grid4, 256, 0, stream>>>(x, F0h, F0l, asr0, adt0, as_, ad_,
                                                    Hb16, 0, N, HID, FIN, 4);
  agg_kernel<8, 32, true><<<gagg, 256, 0, stream>>>(Hb16, as_, ad_, row_start, csr_src, b0,
                                                    act, N);

  // ---- layer 1: SPLIT-M EXPERIMENT (two half dispatches) ----
  int Mhalf = (mb / 2) * 64;       // 156*64 = 9984
  int mbh1 = (Mhalf + 63) / 64;                    // 156
  int mbh2 = (N - Mhalf + 63) / 64;                // 157
  int g4h1 = 8 * 4 * ((mbh1 + 7) / 8);
  int g4h2 = 8 * 4 * ((mbh2 + 7) / 8);
  gemm_mfma<true, false><<<g4h1, 256, 0, stream>>>(act, F1h, F1l, asr1, adt1, as_, ad_,
                                                   Hb16, 0, Mhalf, HID, HID, 4);
  gemm_mfma<true, false><<<g4h2, 256, 0, stream>>>(act, F1h, F1l, asr1, adt1, as_, ad_,
                                                   Hb16, Mhalf, N, HID, HID, 4);
  agg_kernel<8, 32, true><<<gagg, 256, 0, stream>>>(Hb16, as_, ad_, row_start, csr_src, b1,
                                                    hpen, N);

  // ---- layer 2: full-M (alpha fused via atomics; as_/ad_ zeroed in prefrag) ----
  gemm_mfma<false, true><<<grid2, 256, 0, stream>>>(hpen, F2h, F2l, asr2, adt2, as_, ad_,
                                                    Hb16, 0, N, OUTC, HID, 2);
  agg_kernel<1, 128, false><<<gagg, 256, 0, stream>>>(Hb16, as_, ad_, row_start, csr_src, b2,
                                                      out2, N);
}

// Round 24
// 219.683 us; speedup vs baseline: 1.0880x; 1.0880x over previous
//
#include <hip/hip_runtime.h>
#include <hip/hip_bf16.h>

// d_out is FLOAT32. h_pen = first N*256 f32, h = next N*128 f32.
// Structural notes (hard-won over 23 rounds):
//  - GEMM dispatch cost ~49us is a fixed floor: invariant to M, K, grid, LDS size,
//    staging style, prefetch depth, store pattern (R14-R23). 2-barrier lockstep regime.
//  - agg is at the 8-XCD gather-redundancy floor (~3.5 TB/s on bf16 rows).
//  - bf16 hi/lo split (3 MFMA) is required: plain bf16 GEMM exceeds the 9.7e-3 threshold.

using bf16 = __hip_bfloat16;

typedef __attribute__((ext_vector_type(8))) short bf16x8;
typedef __attribute__((ext_vector_type(4))) short short4v;
typedef __attribute__((ext_vector_type(4))) float f32x4;
typedef __attribute__((ext_vector_type(2))) unsigned int uint2v;

__device__ __forceinline__ float u2f(unsigned u) { union { float f; unsigned u; } c; c.u = u; return c.f; }
__device__ __forceinline__ unsigned f2u(float x) { union { float f; unsigned u; } c; c.f = x; return c.u; }
__device__ __forceinline__ short bfbits(float x) {
  unsigned xu = f2u(x);
  return (short)((xu + 0x7FFF + ((xu >> 16) & 1)) >> 16);
}

// ============================ CSR build (dst-sorted) ============================
__global__ void hist_kernel(const int* __restrict__ ei, int E, int N, int* __restrict__ cnt) {
  int e = blockIdx.x * 256 + threadIdx.x;
  if (e >= E + N) return;
  int dst = (e < E) ? ei[E + e] : (e - E);
  atomicAdd(&cnt[dst], 1);
}

__global__ __launch_bounds__(1024) void scan_kernel(const int* __restrict__ cnt,
                                                    int* __restrict__ row_start, int N) {
  __shared__ int part[1024];
  int t = threadIdx.x;
  int chunk = (N + 1023) / 1024;
  int lo = t * chunk; if (lo > N) lo = N;
  int hi = lo + chunk; if (hi > N) hi = N;
  int s = 0;
  for (int i = lo; i < hi; ++i) s += cnt[i];
  part[t] = s;
  __syncthreads();
  for (int off = 1; off < 1024; off <<= 1) {
    int add = (t >= off) ? part[t - off] : 0;
    __syncthreads();
    part[t] += add;
    __syncthreads();
  }
  int run = part[t] - s;
  for (int i = lo; i < hi; ++i) { row_start[i] = run; run += cnt[i]; }
  if (t == 1023) row_start[N] = part[1023];
}

__global__ void scatter_kernel(const int* __restrict__ ei, int E, int N,
                               const int* __restrict__ row_start, int* __restrict__ cursor,
                               int* __restrict__ csr_src) {
  int e = blockIdx.x * 256 + threadIdx.x;
  if (e >= E + N) return;
  int src, dst;
  if (e < E) { src = ei[e]; dst = ei[E + e]; }
  else       { src = e - E; dst = e - E; }
  int pos = atomicAdd(&cursor[dst], 1);
  csr_src[row_start[dst] + pos] = src;
}

// ============================ W (f32) -> split + MFMA fragment order + zero as_/ad_ ============================
// F[((jb*ktmax + kt32)*64 + lane)*8 + e]: col=jb*16+(lane&15);
// e<4 -> k=kt32*32+(lane>>4)*4+e ; e>=4 -> +16. Replicates make_frag's lane->k map.
__global__ void prefrag_kernel(const float* __restrict__ W0, const float* __restrict__ W1,
                               const float* __restrict__ W2,
                               unsigned short* __restrict__ F0h, unsigned short* __restrict__ F0l,
                               unsigned short* __restrict__ F1h, unsigned short* __restrict__ F1l,
                               unsigned short* __restrict__ F2h, unsigned short* __restrict__ F2l,
                               float* __restrict__ z0, float* __restrict__ z1,
                               int c0, int c1, int c2, int nz) {
  int id = blockIdx.x * 256 + threadIdx.x;
  const float* W; unsigned short *Fh, *Fl; int K, ktmax, rid;
  if (id < c0)                { W = W0; Fh = F0h; Fl = F0l; K = 512; ktmax = 16; rid = id; }
  else if (id < c0 + c1)      { W = W1; Fh = F1h; Fl = F1l; K = 256; ktmax = 8;  rid = id - c0; }
  else if (id < c0 + c1 + c2) { W = W2; Fh = F2h; Fl = F2l; K = 256; ktmax = 8;  rid = id - c0 - c1; }
  else {
    int zi = id - c0 - c1 - c2;          // zero tail: as_[0..nz), ad_[0..nz)
    if (zi < nz) z0[zi] = 0.f;
    else if (zi < 2 * nz) z1[zi - nz] = 0.f;
    return;
  }
  int lane = rid & 63;
  int blk  = rid >> 6;              // jb*ktmax + kt32
  int jb   = blk / ktmax;
  int kt32 = blk % ktmax;
  int lr = lane & 15, g = lane >> 4;
  const float* s = W + (size_t)(jb * 16 + lr) * K + kt32 * 32;
  short4v h0, h1, l0, l1;
#pragma unroll
  for (int e = 0; e < 4; ++e) {
    float a = s[g * 4 + e];
    short hb = bfbits(a);
    h0[e] = hb; l0[e] = bfbits(a - u2f(((unsigned)(unsigned short)hb) << 16));
    float b = s[16 + g * 4 + e];
    short hb2 = bfbits(b);
    h1[e] = hb2; l1[e] = bfbits(b - u2f(((unsigned)(unsigned short)hb2) << 16));
  }
  size_t o = ((size_t)blk * 64 + lane) * 8;
  *(short4v*)(Fh + o)     = h0;
  *(short4v*)(Fh + o + 4) = h1;
  *(short4v*)(Fl + o)     = l0;
  *(short4v*)(Fl + o + 4) = l1;
}

// ============================ MFMA GEMM 64x64: A via LDS, B direct from fragment-ordered global ============================
#define LDP 40  // LDS pitch in shorts

__device__ __forceinline__ bf16x8 make_frag(const short* S, int row, int g) {
  short4v klo = *(const short4v*)&S[row * LDP + g * 4];
  short4v khi = *(const short4v*)&S[row * LDP + 16 + g * 4];
  bf16x8 r;
#pragma unroll
  for (int i = 0; i < 4; ++i) { r[i] = klo[i]; r[i + 4] = khi[i]; }
  return r;
}

template <bool FUSE8, bool FUSE1>
__global__ __launch_bounds__(256) void gemm_mfma(const float* __restrict__ Af,
                                                 const unsigned short* __restrict__ Fh,
                                                 const unsigned short* __restrict__ Fl,
                                                 const float* __restrict__ Asrc,
                                                 const float* __restrict__ Adst,
                                                 float* __restrict__ as_,
                                                 float* __restrict__ ad_,
                                                 unsigned short* __restrict__ C16,
                                                 int M, int Nn, int K, int NB) {
  // XCD-aware: same-bm blocks differ by 8 in id -> same XCD -> A panel L2 reuse.
  int id = blockIdx.x;
  int r8 = id & 7;
  int q  = id >> 3;
  int bn = q % NB;
  int bm = r8 + 8 * (q / NB);
  if (bm * 64 >= M) return;

  __shared__ short Ah[64 * LDP];
  __shared__ short Al[64 * LDP];
  int t = threadIdx.x;
  int w = t >> 6, l = t & 63;
  int g = l >> 4, lr = l & 15;
  int ktmax = K >> 5;

  f32x4 acc[4];
#pragma unroll
  for (int j = 0; j < 4; ++j) acc[j] = (f32x4)(0.f);

  int srow = t >> 2;            // 0..63
  int sseg = (t & 3) * 8;       // 0,8,16,24
  int gm = bm * 64 + srow;
  const float* Abase = Af + (size_t)gm * K + sseg;
  const unsigned short* FhL = Fh + (size_t)l * 8;
  const unsigned short* FlL = Fl + (size_t)l * 8;

  // ---- prologue: A iteration 0 ----
  f32x4 va0 = (f32x4)(0.f), va1 = (f32x4)(0.f);
  if (gm < M) { va0 = *(const f32x4*)(Abase); va1 = *(const f32x4*)(Abase + 4); }

  for (int kt32 = 0; kt32 < ktmax; ++kt32) {
    short4v h0, l0, h1, l1;
#pragma unroll
    for (int i = 0; i < 4; ++i) {
      short hb0 = bfbits(va0[i]);
      l0[i] = bfbits(va0[i] - u2f(((unsigned)(unsigned short)hb0) << 16));
      h0[i] = hb0;
      short hb1 = bfbits(va1[i]);
      l1[i] = bfbits(va1[i] - u2f(((unsigned)(unsigned short)hb1) << 16));
      h1[i] = hb1;
    }
    __syncthreads();
    *(short4v*)&Ah[srow * LDP + sseg]     = h0;
    *(short4v*)&Ah[srow * LDP + sseg + 4] = h1;
    *(short4v*)&Al[srow * LDP + sseg]     = l0;
    *(short4v*)&Al[srow * LDP + sseg + 4] = l1;
    __syncthreads();

    // ---- prefetch next A tile (overlaps MFMA + B loads) ----
    if (kt32 + 1 < ktmax) {
      int k2 = (kt32 + 1) << 5;
      if (gm < M) { va0 = *(const f32x4*)(Abase + k2); va1 = *(const f32x4*)(Abase + k2 + 4); }
    }

    int arow = w * 16 + lr;
    bf16x8 ah = make_frag(Ah, arow, g);
    bf16x8 al = make_frag(Al, arow, g);
#pragma unroll
    for (int j = 0; j < 4; ++j) {
      size_t fo = ((size_t)((bn * 4 + j) * ktmax + kt32) * 64) * 8;
      bf16x8 bh = *(const bf16x8*)(FhL + fo);
      bf16x8 bl = *(const bf16x8*)(FlL + fo);
      acc[j] = __builtin_amdgcn_mfma_f32_16x16x32_bf16(ah, bh, acc[j], 0, 0, 0);
      acc[j] = __builtin_amdgcn_mfma_f32_16x16x32_bf16(al, bh, acc[j], 0, 0, 0);
      acc[j] = __builtin_amdgcn_mfma_f32_16x16x32_bf16(ah, bl, acc[j], 0, 0, 0);
    }
  }

  // ---- C16 write. C/D layout (HW-verified m89): col = lane&15, row = (lane>>4)*4 + reg ----
#pragma unroll
  for (int j = 0; j < 4; ++j) {
#pragma unroll
    for (int r = 0; r < 4; ++r) {
      int row = bm * 64 + w * 16 + g * 4 + r;
      int col = bn * 64 + j * 16 + lr;
      if (row < M) C16[(size_t)row * Nn + col] = (unsigned short)bfbits(acc[j][r]);
    }
  }

  // ---- fused alpha (H=8): block covers heads 2bn, 2bn+1 ----
  if constexpr (FUSE8) {
    float cs[4], cd[4];
#pragma unroll
    for (int j = 0; j < 4; ++j) {
      cs[j] = Asrc[bn * 64 + j * 16 + lr];
      cd[j] = Adst[bn * 64 + j * 16 + lr];
    }
#pragma unroll
    for (int r = 0; r < 4; ++r) {
      float sA0 = acc[0][r] * cs[0] + acc[1][r] * cs[1];
      float sA1 = acc[2][r] * cs[2] + acc[3][r] * cs[3];
      float sD0 = acc[0][r] * cd[0] + acc[1][r] * cd[1];
      float sD1 = acc[2][r] * cd[2] + acc[3][r] * cd[3];
#pragma unroll
      for (int mask = 1; mask < 16; mask <<= 1) {
        sA0 += __shfl_xor(sA0, mask);
        sA1 += __shfl_xor(sA1, mask);
        sD0 += __shfl_xor(sD0, mask);
        sD1 += __shfl_xor(sD1, mask);
      }
      if (lr == 0) {
        int row = bm * 64 + w * 16 + g * 4 + r;
        if (row < M) {
          as_[row * 8 + bn * 2]     = sA0;
          as_[row * 8 + bn * 2 + 1] = sA1;
          ad_[row * 8 + bn * 2]     = sD0;
          ad_[row * 8 + bn * 2 + 1] = sD1;
        }
      }
    }
  }

  // ---- fused alpha (H=1, C=128): partial 64-col dot, atomicAdd (pre-zeroed) ----
  if constexpr (FUSE1) {
    float cs[4], cd[4];
#pragma unroll
    for (int j = 0; j < 4; ++j) {
      cs[j] = Asrc[bn * 64 + j * 16 + lr];
      cd[j] = Adst[bn * 64 + j * 16 + lr];
    }
#pragma unroll
    for (int r = 0; r < 4; ++r) {
      float sA = acc[0][r] * cs[0] + acc[1][r] * cs[1] + acc[2][r] * cs[2] + acc[3][r] * cs[3];
      float sD = acc[0][r] * cd[0] + acc[1][r] * cd[1] + acc[2][r] * cd[2] + acc[3][r] * cd[3];
#pragma unroll
      for (int mask = 1; mask < 16; mask <<= 1) {
        sA += __shfl_xor(sA, mask);
        sD += __shfl_xor(sD, mask);
      }
      if (lr == 0) {
        int row = bm * 64 + w * 16 + g * 4 + r;
        if (row < M) {
          atomicAdd(&as_[row], sA);
          atomicAdd(&ad_[row], sD);
        }
      }
    }
  }
}

// ============================ softmax + aggregate (bf16 gather, 4-deep, 1 wave/node) ============================
template <int H, int C, bool RELU>
__global__ __launch_bounds__(64) void agg_kernel(const unsigned short* __restrict__ Hb16,
                                                 const float* __restrict__ as_,
                                                 const float* __restrict__ ad_,
                                                 const int* __restrict__ row_start,
                                                 const int* __restrict__ csr_src,
                                                 const float* __restrict__ bias,
                                                 float* __restrict__ out, int N) {
  int n = blockIdx.x;
  if (n >= N) return;
  int l = threadIdx.x;
  int s = row_start[n], e = row_start[n + 1];

  constexpr int LPH = 64 / H;
  constexpr int CPL = C / LPH;
  constexpr int HC = H * C;
  int h2 = l / LPH;
  int cb = (l % LPH) * CPL;
  float ad2 = ad_[n * H + h2];

  float acc[CPL];
#pragma unroll
  for (int c = 0; c < CPL; ++c) acc[c] = 0.f;
  float denom = 0.f;

  auto lrelu = [](float x) { return x > 0.f ? x : 0.2f * x; };

  int j = s;
  for (; j + 3 < e; j += 4) {
    int s0 = csr_src[j], s1 = csr_src[j + 1], s2 = csr_src[j + 2], s3 = csr_src[j + 3];
    float x0 = as_[s0 * H + h2], x1 = as_[s1 * H + h2];
    float x2 = as_[s2 * H + h2], x3 = as_[s3 * H + h2];
    const unsigned short* hp0 = Hb16 + (size_t)s0 * HC + h2 * C + cb;
    const unsigned short* hp1 = Hb16 + (size_t)s1 * HC + h2 * C + cb;
    const unsigned short* hp2 = Hb16 + (size_t)s2 * HC + h2 * C + cb;
    const unsigned short* hp3 = Hb16 + (size_t)s3 * HC + h2 * C + cb;
    float p0 = __expf(lrelu(x0 + ad2)), p1 = __expf(lrelu(x1 + ad2));
    float p2 = __expf(lrelu(x2 + ad2)), p3 = __expf(lrelu(x3 + ad2));
    denom += (p0 + p1) + (p2 + p3);
    if constexpr (CPL == 4) {
      uint2v u0 = *(const uint2v*)hp0;
      uint2v u1 = *(const uint2v*)hp1;
      uint2v u2 = *(const uint2v*)hp2;
      uint2v u3 = *(const uint2v*)hp3;
#pragma unroll
      for (int c = 0; c < 2; ++c) {
        acc[2 * c]     += p0 * u2f(u0[c] << 16)         + p1 * u2f(u1[c] << 16)
                        + p2 * u2f(u2[c] << 16)         + p3 * u2f(u3[c] << 16);
        acc[2 * c + 1] += p0 * u2f(u0[c] & 0xFFFF0000u) + p1 * u2f(u1[c] & 0xFFFF0000u)
                        + p2 * u2f(u2[c] & 0xFFFF0000u) + p3 * u2f(u3[c] & 0xFFFF0000u);
      }
    } else {
      unsigned u0 = *(const unsigned*)hp0;
      unsigned u1 = *(const unsigned*)hp1;
      unsigned u2 = *(const unsigned*)hp2;
      unsigned u3 = *(const unsigned*)hp3;
      acc[0] += p0 * u2f(u0 << 16)         + p1 * u2f(u1 << 16)
              + p2 * u2f(u2 << 16)         + p3 * u2f(u3 << 16);
      acc[1] += p0 * u2f(u0 & 0xFFFF0000u) + p1 * u2f(u1 & 0xFFFF0000u)
              + p2 * u2f(u2 & 0xFFFF0000u) + p3 * u2f(u3 & 0xFFFF0000u);
    }
  }
  for (; j < e; ++j) {
    int s0 = csr_src[j];
    float p0 = __expf(lrelu(as_[s0 * H + h2] + ad2));
    denom += p0;
    const unsigned short* hp0 = Hb16 + (size_t)s0 * HC + h2 * C + cb;
    if constexpr (CPL == 4) {
      uint2v u0 = *(const uint2v*)hp0;
#pragma unroll
      for (int c = 0; c < 2; ++c) {
        acc[2 * c]     += p0 * u2f(u0[c] << 16);
        acc[2 * c + 1] += p0 * u2f(u0[c] & 0xFFFF0000u);
      }
    } else {
      unsigned u0 = *(const unsigned*)hp0;
      acc[0] += p0 * u2f(u0 << 16);
      acc[1] += p0 * u2f(u0 & 0xFFFF0000u);
    }
  }

  float inv = 1.f / (denom + 1e-16f);
#pragma unroll
  for (int c = 0; c < CPL; ++c) {
    float v = acc[c] * inv + bias[h2 * C + cb + c];
    if (RELU) v = fmaxf(v, 0.f);
    out[(size_t)n * HC + h2 * C + cb + c] = v;
  }
}

// ============================ launch ============================
extern "C" void kernel_launch(void* const* d_in, const int* in_sizes, int n_in,
                              void* d_out, int out_size, void* d_ws, size_t ws_size,
                              hipStream_t stream) {
  const float* x    = (const float*)d_in[0];
  const int*   ei   = (const int*)d_in[1];
  const float* W0   = (const float*)d_in[2];
  const float* asr0 = (const float*)d_in[3];
  const float* adt0 = (const float*)d_in[4];
  const float* b0   = (const float*)d_in[5];
  const float* W1   = (const float*)d_in[6];
  const float* asr1 = (const float*)d_in[7];
  const float* adt1 = (const float*)d_in[8];
  const float* b1   = (const float*)d_in[9];
  const float* W2   = (const float*)d_in[10];
  const float* asr2 = (const float*)d_in[11];
  const float* adt2 = (const float*)d_in[12];
  const float* b2   = (const float*)d_in[13];

  const int FIN = 512, HID = 256, OUTC = 128;
  int N = in_sizes[0] / FIN;          // 20000
  int E = in_sizes[1] / 2;            // 320000
  int Etot = E + N;

  char* ws = (char*)d_ws;
  size_t off = 0;
  auto alloc = [&](size_t bytes) -> void* {
    void* p = ws + off;
    off = (off + bytes + 255) & ~(size_t)255;
    return p;
  };
  int* cnt       = (int*)alloc((size_t)N * 4);
  int* cursor    = (int*)alloc((size_t)N * 4);
  int* row_start = (int*)alloc((size_t)(N + 1) * 4);
  int* csr_src   = (int*)alloc((size_t)Etot * 4);
  float* as_     = (float*)alloc((size_t)N * 8 * 4);
  float* ad_     = (float*)alloc((size_t)N * 8 * 4);
  unsigned short* Hb16 = (unsigned short*)alloc((size_t)N * HID * 2);
  float* act     = (float*)alloc((size_t)N * HID * 4);
  unsigned short* F0h = (unsigned short*)alloc((size_t)HID * FIN * 2);
  unsigned short* F0l = (unsigned short*)alloc((size_t)HID * FIN * 2);
  unsigned short* F1h = (unsigned short*)alloc((size_t)HID * HID * 2);
  unsigned short* F1l = (unsigned short*)alloc((size_t)HID * HID * 2);
  unsigned short* F2h = (unsigned short*)alloc((size_t)OUTC * HID * 2);
  unsigned short* F2l = (unsigned short*)alloc((size_t)OUTC * HID * 2);

  float* hpen = (float*)d_out;
  float* out2 = (float*)d_out + (size_t)N * HID;

  // ---- split+fragment weights AND zero as_/ad_ (one launch) ----
  int c0 = (HID / 16) * (FIN / 32) * 64;
  int c1 = (HID / 16) * (HID / 32) * 64;
  int c2 = (OUTC / 16) * (HID / 32) * 64;
  int total = c0 + c1 + c2 + 2 * N;
  prefrag_kernel<<<(total + 255) / 256, 256, 0, stream>>>(
      W0, W1, W2, F0h, F0l, F1h, F1l, F2h, F2l, as_, ad_, c0, c1, c2, N);

  // ---- CSR build ----
  (void)hipMemsetAsync(cnt, 0, (size_t)((char*)cursor - (char*)cnt) + (size_t)N * 4, stream);
  int eb = (Etot + 255) / 256;
  hist_kernel<<<eb, 256, 0, stream>>>(ei, E, N, cnt);
  scan_kernel<<<1, 1024, 0, stream>>>(cnt, row_start, N);
  scatter_kernel<<<eb, 256, 0, stream>>>(ei, E, N, row_start, cursor, csr_src);

  int mb = (N + 63) / 64;          // 313
  int mb8 = (mb + 7) / 8;          // 40
  int grid4 = 8 * 4 * mb8;         // NB=4 (HID=256)
  int grid2 = 8 * 2 * mb8;         // NB=2 (OUTC=128)

  // ---- layer 0: 512 -> 8x32, relu (alpha fused) ----
  gemm_mfma<true, false><<<grid4, 256, 0, stream>>>(x, F0h, F0l, asr0, adt0, as_, ad_,
                                                    Hb16, N, HID, FIN, 4);
  agg_kernel<8, 32, true><<<N, 64, 0, stream>>>(Hb16, as_, ad_, row_start, csr_src, b0,
                                                act, N);

  // ---- layer 1: 256 -> 8x32, relu (alpha fused; h_pen -> d_out f32) ----
  gemm_mfma<true, false><<<grid4, 256, 0, stream>>>(act, F1h, F1l, asr1, adt1, as_, ad_,
                                                    Hb16, N, HID, HID, 4);
  agg_kernel<8, 32, true><<<N, 64, 0, stream>>>(Hb16, as_, ad_, row_start, csr_src, b1,
                                                hpen, N);

  // ---- layer 2: 256 -> 128, 1 head, no relu (alpha fused via atomics; zeroed in prefrag) ----
  gemm_mfma<false, true><<<grid2, 256, 0, stream>>>(hpen, F2h, F2l, asr2, adt2, as_, ad_,
                                                    Hb16, N, OUTC, HID, 2);
  agg_kernel<1, 128, false><<<N, 64, 0, stream>>>(Hb16, as_, ad_, row_start, csr_src, b2,
                                                  out2, N);
}